// Round 7
// baseline (140.951 us; speedup 1.0000x reference)
//
#include <hip/hip_runtime.h>

#define NSEQ 4096
#define EDIM 1024

// ws layout (float offsets)
#define OFF_HP  0u        // {h_loc, P_inc} [64 chain][4096 t] float2 = 2 MB
#define OFF_SUM 524288u   // {h_last, P_prod} [64 chain][64 chunk] float2 = 32 KB

__device__ __forceinline__ void fma4(float4& a, float xv, const float4& b) {
    a.x = fmaf(xv, b.x, a.x);
    a.y = fmaf(xv, b.y, a.y);
    a.z = fmaf(xv, b.z, a.z);
    a.w = fmaf(xv, b.w, a.w);
}

// ---------------------------------------------------------------------------
// kA: Bx = x @ B_in for 64 rows x FULL e (1024) + softplus/decay + 64-step
// chunk-local scan, all in one kernel. 256 blocks x 512 threads (8 waves,
// launch_bounds(512,2) -> 256-VGPR budget; ~180 demanded, no spill).
// NO LDS staging (waves partition e -> zero cross-wave x reuse; round 6
// proved staging was pure overhead): each thread loads its 32 float4 of x
// (row = lane, e-slice = wave-uniform [wu*128, +128)) straight into regs —
// 512 B/thread in flight, no barriers until the reduce. B via s_loads.
// Differences vs round-4's 48 us failure: 1 barrier total (vs 17), explicit
// register residency (vs 52/32-VGPR starvation + 33 MB scratch), deep MLP.
// Tail: 8-wave LDS reduce -> wave wu scans s = wu*2+j over the 64 t (lane=t),
// writes {h_loc,P_inc} float2 + per-chunk summary. PBX intermediate GONE.
// ---------------------------------------------------------------------------
__global__ __launch_bounds__(512, 2) void kA_bxscan(const float* __restrict__ x,
                                                    const float* __restrict__ A,
                                                    const float* __restrict__ Bin,
                                                    float* __restrict__ ws) {
    __shared__ float red[8 * 64 * 17];   // 34.8 KB (reduction only)
    const int tid  = threadIdx.x;
    const int lane = tid & 63;                                  // row (= t)
    const int wu   = __builtin_amdgcn_readfirstlane(tid) >> 6;  // wave 0..7
    const int r0   = blockIdx.x * 64;      // global row base (b*4096 + n0)
    const int b    = r0 >> 12;
    const int n0   = r0 & 4095;

    const float4* xf4 = (const float4*)x;
    const float4* Bf4 = (const float4*)Bin;

    // this thread's x: row r0+lane, e in [wu*128, wu*128+128) = 32 float4
    float4 xr[32];
    const size_t rowb = (size_t)(r0 + lane) * 256 + wu * 32;
#pragma unroll
    for (int j = 0; j < 32; j++) xr[j] = xf4[rowb + j];

    float acc[16];
#pragma unroll
    for (int s = 0; s < 16; s++) acc[s] = 0.f;

#pragma unroll
    for (int j = 0; j < 32; j++) {
        const float4 xq = xr[j];
        const float xs[4] = {xq.x, xq.y, xq.z, xq.w};
#pragma unroll
        for (int m = 0; m < 4; m++) {
            const int e = wu * 128 + j * 4 + m;    // wave-uniform -> s_loads
            const float4 b0 = Bf4[e * 4 + 0];
            const float4 b1 = Bf4[e * 4 + 1];
            const float4 b2 = Bf4[e * 4 + 2];
            const float4 b3 = Bf4[e * 4 + 3];
            const float xv = xs[m];
            acc[0]  = fmaf(xv, b0.x, acc[0]);  acc[1]  = fmaf(xv, b0.y, acc[1]);
            acc[2]  = fmaf(xv, b0.z, acc[2]);  acc[3]  = fmaf(xv, b0.w, acc[3]);
            acc[4]  = fmaf(xv, b1.x, acc[4]);  acc[5]  = fmaf(xv, b1.y, acc[5]);
            acc[6]  = fmaf(xv, b1.z, acc[6]);  acc[7]  = fmaf(xv, b1.w, acc[7]);
            acc[8]  = fmaf(xv, b2.x, acc[8]);  acc[9]  = fmaf(xv, b2.y, acc[9]);
            acc[10] = fmaf(xv, b2.z, acc[10]); acc[11] = fmaf(xv, b2.w, acc[11]);
            acc[12] = fmaf(xv, b3.x, acc[12]); acc[13] = fmaf(xv, b3.y, acc[13]);
            acc[14] = fmaf(xv, b3.z, acc[14]); acc[15] = fmaf(xv, b3.w, acc[15]);
        }
    }

    // cross-wave reduction: red[8 waves][64 rows][17]
    {
        const int rb = (wu * 64 + lane) * 17;
#pragma unroll
        for (int s = 0; s < 16; s++) red[rb + s] = acc[s];
    }
    __syncthreads();

    // softplus -> decay -> 64-step wave scan; wave wu handles s = wu*2 + j
    const int chunk = n0 >> 6;     // == blockIdx.x & 63
    float2* HP = (float2*)(ws + OFF_HP);
    float2* SU = (float2*)(ws + OFF_SUM);
#pragma unroll
    for (int jj = 0; jj < 2; ++jj) {
        const int s = wu * 2 + jj;                 // wave-uniform
        float bx = 0.f;
#pragma unroll
        for (int wp = 0; wp < 8; ++wp)
            bx += red[(wp * 64 + lane) * 17 + s];
        const float Ae = expf(A[s]);
        const float sp = fmaxf(bx, 0.f) + log1pf(expf(-fabsf(bx)));
        const float de = expf(-Ae * sp);
        // wave-inclusive scan of (P,h): h' = h_left*P_right + h_right
        float Pi = de, hi = bx;
#pragma unroll
        for (int off = 1; off < 64; off <<= 1) {
            float Pp = __shfl_up(Pi, off, 64);
            float hp = __shfl_up(hi, off, 64);
            if (lane >= off) { hi = fmaf(hp, Pi, hi); Pi *= Pp; }
        }
        const int chain = b * 16 + s;
        HP[(size_t)chain * NSEQ + n0 + lane] = make_float2(hi, Pi);
        if (lane == 63) SU[chain * 64 + chunk] = make_float2(hi, Pi);
    }
}

// ---------------------------------------------------------------------------
// kB: carry-in H = fma-compose of <=63 chunk summaries (32 KB, L2-hot;
// loads pipelined by unroll, dep chain = 63 FMAs ~ 250 cyc), then
// h = fma(P_inc, H, h_loc) into a 16x20 LDS tile (pitch 20: 16B-aligned
// rows -> broadcast ds_read_b128), then y[b,t,e] = sum_s h[t,s]*C[s,e]
// (+ x*D slow path). 1024 blocks x 256 threads, 4 blocks/CU.
// ---------------------------------------------------------------------------
__global__ __launch_bounds__(256) void kB_out(const float* __restrict__ x,
                                              const float* __restrict__ C,
                                              const float* __restrict__ D,
                                              const float* __restrict__ ws,
                                              float* __restrict__ out) {
    __shared__ __align__(16) float sh[16 * 20];
    const int tid = threadIdx.x;
    const int blk = blockIdx.x;
    const int tc  = blk & 255;
    const int b   = blk >> 8;
    const int t0  = tc * 16;

    {   // reconstruct h[tt][s]: thread (s = tid>>4, tt = tid&15)
        const int s  = tid >> 4;
        const int tt = tid & 15;
        const int chain = b * 16 + s;
        const int t  = t0 + tt;
        const int c0 = t >> 6;             // uniform per block (16 <= 64)
        const float2* SU = (const float2*)(ws + OFF_SUM);
        float H = 0.f;                     // scan state entering this chunk
#pragma unroll 4
        for (int c = 0; c < c0; ++c) {
            const float2 su = SU[chain * 64 + c];
            H = fmaf(H, su.y, su.x);
        }
        const float2 hp = ((const float2*)(ws + OFF_HP))[(size_t)chain * NSEQ + t];
        sh[tt * 20 + s] = fmaf(hp.y, H, hp.x);
    }

    const float4* C4 = (const float4*)C;  // [16][256] float4
    float4 creg[16];
#pragma unroll
    for (int s = 0; s < 16; s++) creg[s] = C4[s * 256 + tid];
    const float4 dreg = ((const float4*)D)[tid];
    const bool needX = __any((dreg.x != 0.f) | (dreg.y != 0.f) |
                             (dreg.z != 0.f) | (dreg.w != 0.f));
    __syncthreads();

    const float4* x4 = (const float4*)x;
    float4* o4 = (float4*)out;
    const size_t rowbase = ((size_t)b * NSEQ + t0) * 256;

    if (needX) {
#pragma unroll 4
        for (int tt = 0; tt < 16; tt++) {
            float4 xv = x4[rowbase + tt * 256 + tid];
            float4 y;
            y.x = xv.x * dreg.x; y.y = xv.y * dreg.y;
            y.z = xv.z * dreg.z; y.w = xv.w * dreg.w;
#pragma unroll
            for (int g = 0; g < 4; g++) {
                const float4 h4 = *(const float4*)&sh[tt * 20 + g * 4];
                fma4(y, h4.x, creg[g * 4 + 0]);
                fma4(y, h4.y, creg[g * 4 + 1]);
                fma4(y, h4.z, creg[g * 4 + 2]);
                fma4(y, h4.w, creg[g * 4 + 3]);
            }
            o4[rowbase + tt * 256 + tid] = y;
        }
    } else {
#pragma unroll 4
        for (int tt = 0; tt < 16; tt++) {
            float4 y = make_float4(0.f, 0.f, 0.f, 0.f);
#pragma unroll
            for (int g = 0; g < 4; g++) {
                const float4 h4 = *(const float4*)&sh[tt * 20 + g * 4];
                fma4(y, h4.x, creg[g * 4 + 0]);
                fma4(y, h4.y, creg[g * 4 + 1]);
                fma4(y, h4.z, creg[g * 4 + 2]);
                fma4(y, h4.w, creg[g * 4 + 3]);
            }
            o4[rowbase + tt * 256 + tid] = y;
        }
    }
}

extern "C" void kernel_launch(void* const* d_in, const int* in_sizes, int n_in,
                              void* d_out, int out_size, void* d_ws, size_t ws_size,
                              hipStream_t stream) {
    const float* x   = (const float*)d_in[0];
    const float* A   = (const float*)d_in[1];
    const float* Bin = (const float*)d_in[2];
    const float* C   = (const float*)d_in[3];
    const float* D   = (const float*)d_in[4];
    float* out = (float*)d_out;
    float* ws  = (float*)d_ws;

    hipLaunchKernelGGL(kA_bxscan, dim3(256),  dim3(512), 0, stream, x, A, Bin, ws);
    hipLaunchKernelGGL(kB_out,    dim3(1024), dim3(256), 0, stream, x, C, D, ws, out);
}

// Round 8
// 134.963 us; speedup vs baseline: 1.0444x; 1.0444x over previous
//
#include <hip/hip_runtime.h>

#define NSEQ 4096
#define EDIM 1024

// ws layout (float offsets)
#define OFF_HP  0u        // {h_loc, P_inc} [64 chain][4096 t] float2 = 2 MB
#define OFF_SUM 524288u   // {h_last, P_prod} [64 chain][64 chunk] float2 = 32 KB

__device__ __forceinline__ void fma4(float4& a, float xv, const float4& b) {
    a.x = fmaf(xv, b.x, a.x);
    a.y = fmaf(xv, b.y, a.y);
    a.z = fmaf(xv, b.z, a.z);
    a.w = fmaf(xv, b.w, a.w);
}

// ---------------------------------------------------------------------------
// kA: Bx = x @ B_in for 64 rows x FULL e (1024) + softplus/decay + 64-step
// chunk-local scan, one kernel. 256 blocks x 1024 threads (16 waves =
// 4 waves/SIMD — same occupancy as the proven round-6 k1; round 7's
// 512-thread variant had only 2 waves/SIMD and was latency-bound at 44 us).
// Wave wu covers e-slice [wu*64, +64): each thread (row = lane) loads 16
// float4 of x into NAMED registers, with sched_barrier(0) between the load
// loop and the FMA loop so the compiler issues ALL 16 loads before any use
// (round 7's VGPR_Count=24 proved it otherwise collapses the queue to ~2
// in-flight loads). VGPR ~105 <= 128 cap from launch_bounds(1024,4).
// B wave-uniform -> s_loads. 1 barrier total. Tail: 16-wave LDS reduce ->
// wave wu scans s = wu over the 64 t (lane = t), writes {h_loc,P_inc} + SU.
// ---------------------------------------------------------------------------
__global__ __launch_bounds__(1024, 4) void kA_bxscan(const float* __restrict__ x,
                                                     const float* __restrict__ A,
                                                     const float* __restrict__ Bin,
                                                     float* __restrict__ ws) {
    __shared__ float red[16 * 64 * 17];   // 69.6 KB (reduction only)
    const int tid  = threadIdx.x;
    const int lane = tid & 63;                                  // row (= t)
    const int wu   = __builtin_amdgcn_readfirstlane(tid) >> 6;  // wave 0..15
    const int r0   = blockIdx.x * 64;      // global row base (b*4096 + n0)
    const int b    = r0 >> 12;
    const int n0   = r0 & 4095;

    const float4* xf4 = (const float4*)x;
    const float4* Bf4 = (const float4*)Bin;

    // this thread's x: row r0+lane, e in [wu*64, wu*64+64) = 16 float4
    float4 xr[16];
    const size_t rowb = (size_t)(r0 + lane) * 256 + wu * 16;
#pragma unroll
    for (int j = 0; j < 16; j++) xr[j] = xf4[rowb + j];

    // force all 16 loads issued (and their dests live) before any consumer
    __builtin_amdgcn_sched_barrier(0);

    float acc[16];
#pragma unroll
    for (int s = 0; s < 16; s++) acc[s] = 0.f;

#pragma unroll
    for (int j = 0; j < 16; j++) {
        const float4 xq = xr[j];
        const float xs[4] = {xq.x, xq.y, xq.z, xq.w};
#pragma unroll
        for (int m = 0; m < 4; m++) {
            const int e = wu * 64 + j * 4 + m;     // wave-uniform -> s_loads
            const float4 b0 = Bf4[e * 4 + 0];
            const float4 b1 = Bf4[e * 4 + 1];
            const float4 b2 = Bf4[e * 4 + 2];
            const float4 b3 = Bf4[e * 4 + 3];
            const float xv = xs[m];
            acc[0]  = fmaf(xv, b0.x, acc[0]);  acc[1]  = fmaf(xv, b0.y, acc[1]);
            acc[2]  = fmaf(xv, b0.z, acc[2]);  acc[3]  = fmaf(xv, b0.w, acc[3]);
            acc[4]  = fmaf(xv, b1.x, acc[4]);  acc[5]  = fmaf(xv, b1.y, acc[5]);
            acc[6]  = fmaf(xv, b1.z, acc[6]);  acc[7]  = fmaf(xv, b1.w, acc[7]);
            acc[8]  = fmaf(xv, b2.x, acc[8]);  acc[9]  = fmaf(xv, b2.y, acc[9]);
            acc[10] = fmaf(xv, b2.z, acc[10]); acc[11] = fmaf(xv, b2.w, acc[11]);
            acc[12] = fmaf(xv, b3.x, acc[12]); acc[13] = fmaf(xv, b3.y, acc[13]);
            acc[14] = fmaf(xv, b3.z, acc[14]); acc[15] = fmaf(xv, b3.w, acc[15]);
        }
    }

    // cross-wave reduction: red[16 waves][64 rows][17]
    {
        const int rb = (wu * 64 + lane) * 17;
#pragma unroll
        for (int s = 0; s < 16; s++) red[rb + s] = acc[s];
    }
    __syncthreads();

    // softplus -> decay -> 64-step wave scan; wave wu handles s = wu
    const int chunk = n0 >> 6;     // == blockIdx.x & 63
    float2* HP = (float2*)(ws + OFF_HP);
    float2* SU = (float2*)(ws + OFF_SUM);
    {
        const int s = wu;                          // wave-uniform
        float bx = 0.f;
#pragma unroll
        for (int wp = 0; wp < 16; ++wp)
            bx += red[(wp * 64 + lane) * 17 + s];
        const float Ae = expf(A[s]);
        const float sp = fmaxf(bx, 0.f) + log1pf(expf(-fabsf(bx)));
        const float de = expf(-Ae * sp);
        // wave-inclusive scan of (P,h): h' = h_left*P_right + h_right
        float Pi = de, hi = bx;
#pragma unroll
        for (int off = 1; off < 64; off <<= 1) {
            float Pp = __shfl_up(Pi, off, 64);
            float hp = __shfl_up(hi, off, 64);
            if (lane >= off) { hi = fmaf(hp, Pi, hi); Pi *= Pp; }
        }
        const int chain = b * 16 + s;
        HP[(size_t)chain * NSEQ + n0 + lane] = make_float2(hi, Pi);
        if (lane == 63) SU[chain * 64 + chunk] = make_float2(hi, Pi);
    }
}

// ---------------------------------------------------------------------------
// kB: carry-in H = fma-compose of <=63 chunk summaries (32 KB, L2-hot),
// then h = fma(P_inc, H, h_loc) into a 16x20 LDS tile (pitch 20:
// 16B-aligned rows -> broadcast ds_read_b128), then
// y[b,t,e] = sum_s h[t,s]*C[s,e] (+ x*D slow path). 1024 blocks x 256 thr.
// ---------------------------------------------------------------------------
__global__ __launch_bounds__(256) void kB_out(const float* __restrict__ x,
                                              const float* __restrict__ C,
                                              const float* __restrict__ D,
                                              const float* __restrict__ ws,
                                              float* __restrict__ out) {
    __shared__ __align__(16) float sh[16 * 20];
    const int tid = threadIdx.x;
    const int blk = blockIdx.x;
    const int tc  = blk & 255;
    const int b   = blk >> 8;
    const int t0  = tc * 16;

    {   // reconstruct h[tt][s]: thread (s = tid>>4, tt = tid&15)
        const int s  = tid >> 4;
        const int tt = tid & 15;
        const int chain = b * 16 + s;
        const int t  = t0 + tt;
        const int c0 = t >> 6;             // uniform per block (16 <= 64)
        const float2* SU = (const float2*)(ws + OFF_SUM);
        float H = 0.f;                     // scan state entering this chunk
#pragma unroll 4
        for (int c = 0; c < c0; ++c) {
            const float2 su = SU[chain * 64 + c];
            H = fmaf(H, su.y, su.x);
        }
        const float2 hp = ((const float2*)(ws + OFF_HP))[(size_t)chain * NSEQ + t];
        sh[tt * 20 + s] = fmaf(hp.y, H, hp.x);
    }

    const float4* C4 = (const float4*)C;  // [16][256] float4
    float4 creg[16];
#pragma unroll
    for (int s = 0; s < 16; s++) creg[s] = C4[s * 256 + tid];
    const float4 dreg = ((const float4*)D)[tid];
    const bool needX = __any((dreg.x != 0.f) | (dreg.y != 0.f) |
                             (dreg.z != 0.f) | (dreg.w != 0.f));
    __syncthreads();

    const float4* x4 = (const float4*)x;
    float4* o4 = (float4*)out;
    const size_t rowbase = ((size_t)b * NSEQ + t0) * 256;

    if (needX) {
#pragma unroll 4
        for (int tt = 0; tt < 16; tt++) {
            float4 xv = x4[rowbase + tt * 256 + tid];
            float4 y;
            y.x = xv.x * dreg.x; y.y = xv.y * dreg.y;
            y.z = xv.z * dreg.z; y.w = xv.w * dreg.w;
#pragma unroll
            for (int g = 0; g < 4; g++) {
                const float4 h4 = *(const float4*)&sh[tt * 20 + g * 4];
                fma4(y, h4.x, creg[g * 4 + 0]);
                fma4(y, h4.y, creg[g * 4 + 1]);
                fma4(y, h4.z, creg[g * 4 + 2]);
                fma4(y, h4.w, creg[g * 4 + 3]);
            }
            o4[rowbase + tt * 256 + tid] = y;
        }
    } else {
#pragma unroll 4
        for (int tt = 0; tt < 16; tt++) {
            float4 y = make_float4(0.f, 0.f, 0.f, 0.f);
#pragma unroll
            for (int g = 0; g < 4; g++) {
                const float4 h4 = *(const float4*)&sh[tt * 20 + g * 4];
                fma4(y, h4.x, creg[g * 4 + 0]);
                fma4(y, h4.y, creg[g * 4 + 1]);
                fma4(y, h4.z, creg[g * 4 + 2]);
                fma4(y, h4.w, creg[g * 4 + 3]);
            }
            o4[rowbase + tt * 256 + tid] = y;
        }
    }
}

extern "C" void kernel_launch(void* const* d_in, const int* in_sizes, int n_in,
                              void* d_out, int out_size, void* d_ws, size_t ws_size,
                              hipStream_t stream) {
    const float* x   = (const float*)d_in[0];
    const float* A   = (const float*)d_in[1];
    const float* Bin = (const float*)d_in[2];
    const float* C   = (const float*)d_in[3];
    const float* D   = (const float*)d_in[4];
    float* out = (float*)d_out;
    float* ws  = (float*)d_ws;

    hipLaunchKernelGGL(kA_bxscan, dim3(256),  dim3(1024), 0, stream, x, A, Bin, ws);
    hipLaunchKernelGGL(kB_out,    dim3(1024), dim3(256),  0, stream, x, C, D, ws, out);
}